// Round 6
// baseline (927.196 us; speedup 1.0000x reference)
//
#include <hip/hip_runtime.h>

typedef __attribute__((ext_vector_type(8))) short bf16x8;
typedef __attribute__((ext_vector_type(4))) short bf16x4;
typedef __attribute__((ext_vector_type(4))) float f32x4;

#define L2E 1.44269504088896340736f
#define QSCL 0.18033688011112042f   // 0.125 * log2(e)

__device__ inline unsigned short f2bf(float f) {
  union { float f; unsigned int u; } x; x.f = f;
  return (unsigned short)((x.u + 0x8000u) >> 16);
}
__device__ inline unsigned int f2bf2(float a, float b) {
  union { float f; unsigned int u; } xa, xb;
  xa.f = a; xb.f = b;
  return ((xa.u + 0x8000u) >> 16) | (((xb.u + 0x8000u) & 0xFFFF0000u));
}

__device__ inline void gl_lds16(const void* g, void* l) {
  __builtin_amdgcn_global_load_lds((const __attribute__((address_space(1))) void*)g,
                                   (__attribute__((address_space(3))) void*)l,
                                   16, 0, 0);
}

// Explicit LDS-DMA drain before each barrier: the compiler's alias-based
// vmcnt tracking dropped the wait in R4 (warm-replay race). Keep always.
__device__ inline void vm_drain() {
  asm volatile("s_waitcnt vmcnt(0)" ::: "memory");
}

// ---------------- fused cast fp32 -> bf16 (x, W_qkv, W_out) ----------------
#define N4_X  2097152   // 8192*1024/4
#define N4_WQ 786432    // 3072*1024/4
#define N4_WO 262144    // 1024*1024/4
__global__ void cast3_kernel(const float* __restrict__ x,
                             const float* __restrict__ wq,
                             const float* __restrict__ wo,
                             unsigned short* __restrict__ xb,
                             unsigned short* __restrict__ wqb,
                             unsigned short* __restrict__ wob) {
  int i = blockIdx.x * blockDim.x + threadIdx.x;
  int st = gridDim.x * blockDim.x;
  for (; i < N4_X + N4_WQ + N4_WO; i += st) {
    const float* src; unsigned short* dst; int j;
    if (i < N4_X)            { src = x;  dst = xb;  j = i; }
    else if (i < N4_X + N4_WQ){ src = wq; dst = wqb; j = i - N4_X; }
    else                     { src = wo; dst = wob; j = i - N4_X - N4_WQ; }
    float4 v = reinterpret_cast<const float4*>(src)[j];
    ushort4 o;
    o.x = f2bf(v.x); o.y = f2bf(v.y); o.z = f2bf(v.z); o.w = f2bf(v.w);
    reinterpret_cast<ushort4*>(dst)[j] = o;
  }
}

// ---------------- QKV GEMM: [8192,1024] x [3072,1024]^T ----------------
// tn<16 (q/k): swapped-operand MFMA -> C^T, lane holds 4 consecutive features
//              at fixed token -> direct b64 stores to [b,h,n,64].
// tn>=16 (v):  normal MFMA, lane holds 4 consecutive tokens at fixed feature
//              -> direct b64 stores to vT [b,h,64,n].
__global__ __launch_bounds__(256, 4) void gemm_qkv(
    const unsigned short* __restrict__ A,
    const unsigned short* __restrict__ Bm,
    unsigned short* __restrict__ qo,
    unsigned short* __restrict__ ko,
    unsigned short* __restrict__ vo) {
  __shared__ unsigned short sA[2][128 * 32];
  __shared__ unsigned short sB[2][128 * 32];
  const int K = 1024;
  const int tid = threadIdx.x;
  const int w = tid >> 6, lane = tid & 63;
  const int l15 = lane & 15, quad = lane >> 4;
  const int wm = (w >> 1) * 64, wn = (w & 1) * 64;
  const int tm = blockIdx.y, tn = blockIdx.x;
  const bool qkmode = (tn < 16);

  const unsigned short* Ab = A + (size_t)(tm * 128) * K;
  const unsigned short* Bb = Bm + (size_t)(tn * 128) * K;

  const int srow = w * 32 + (lane >> 2);
  const int scol = (((lane & 3) ^ ((lane >> 3) & 3))) * 8;   // swizzled content chunk
  const int rsw = (l15 >> 1) & 3;                            // read-side swizzle key

  const f32x4 fz = {0.f, 0.f, 0.f, 0.f};
  f32x4 acc[4][4];
#pragma unroll
  for (int i = 0; i < 4; i++)
#pragma unroll
    for (int j = 0; j < 4; j++) acc[i][j] = fz;

  gl_lds16(Ab + (size_t)srow * K + scol,        &sA[0][(w * 32) * 32]);
  gl_lds16(Ab + (size_t)(srow + 16) * K + scol, &sA[0][(w * 32 + 16) * 32]);
  gl_lds16(Bb + (size_t)srow * K + scol,        &sB[0][(w * 32) * 32]);
  gl_lds16(Bb + (size_t)(srow + 16) * K + scol, &sB[0][(w * 32 + 16) * 32]);

  int buf = 0;
  for (int k0 = 0; k0 < K; k0 += 32) {
    vm_drain();
    __syncthreads();
    if (k0 + 32 < K) {
      int nb = buf ^ 1, kn = k0 + 32;
      gl_lds16(Ab + (size_t)srow * K + kn + scol,        &sA[nb][(w * 32) * 32]);
      gl_lds16(Ab + (size_t)(srow + 16) * K + kn + scol, &sA[nb][(w * 32 + 16) * 32]);
      gl_lds16(Bb + (size_t)srow * K + kn + scol,        &sB[nb][(w * 32) * 32]);
      gl_lds16(Bb + (size_t)(srow + 16) * K + kn + scol, &sB[nb][(w * 32 + 16) * 32]);
    }
    bf16x8 af[4], bfr[4];
#pragma unroll
    for (int mt = 0; mt < 4; mt++)
      af[mt] = *(const bf16x8*)&sA[buf][(wm + mt * 16 + l15) * 32 + ((quad ^ rsw) << 3)];
#pragma unroll
    for (int nt = 0; nt < 4; nt++)
      bfr[nt] = *(const bf16x8*)&sB[buf][(wn + nt * 16 + l15) * 32 + ((quad ^ rsw) << 3)];
    if (qkmode) {
#pragma unroll
      for (int mt = 0; mt < 4; mt++)
#pragma unroll
        for (int nt = 0; nt < 4; nt++)
          acc[mt][nt] = __builtin_amdgcn_mfma_f32_16x16x32_bf16(bfr[nt], af[mt], acc[mt][nt], 0, 0, 0);
    } else {
#pragma unroll
      for (int mt = 0; mt < 4; mt++)
#pragma unroll
        for (int nt = 0; nt < 4; nt++)
          acc[mt][nt] = __builtin_amdgcn_mfma_f32_16x16x32_bf16(af[mt], bfr[nt], acc[mt][nt], 0, 0, 0);
    }
    buf ^= 1;
  }

  const int m0 = tm * 128;
  const int bb = m0 >> 10, n0 = m0 & 1023;
  const int cbase = (tn * 128) & 1023;

  if (qkmode) {
    const int which = tn >> 3;                 // 0:q 1:k
    const float scl = (which == 0) ? QSCL : 1.0f;
    unsigned short* dst = (which == 0) ? qo : ko;
#pragma unroll
    for (int mt = 0; mt < 4; mt++) {
      int tok = n0 + wm + mt * 16 + l15;
#pragma unroll
      for (int nt = 0; nt < 4; nt++) {
        int c = cbase + wn + nt * 16 + quad * 4;
        int hh = c >> 6, d0 = c & 63;
        uint2 val;
        val.x = f2bf2(acc[mt][nt][0] * scl, acc[mt][nt][1] * scl);
        val.y = f2bf2(acc[mt][nt][2] * scl, acc[mt][nt][3] * scl);
        *(uint2*)&dst[(((size_t)bb * 16 + hh) * 1024 + tok) * 64 + d0] = val;
      }
    }
  } else {
#pragma unroll
    for (int mt = 0; mt < 4; mt++) {
      int tok = n0 + wm + mt * 16 + quad * 4;
#pragma unroll
      for (int nt = 0; nt < 4; nt++) {
        int c = cbase + wn + nt * 16 + l15;
        int hh = c >> 6, dd = c & 63;
        uint2 val;
        val.x = f2bf2(acc[mt][nt][0], acc[mt][nt][1]);
        val.y = f2bf2(acc[mt][nt][2], acc[mt][nt][3]);
        *(uint2*)&vo[(((size_t)bb * 16 + hh) * 64 + dd) * 1024 + tok] = val;
      }
    }
  }
}

// ---------------- flash attention: S^T, register PV, scalar-di bias, MFMA rsum ----
__global__ __launch_bounds__(256, 4) void attn_kernel(
    const unsigned short* __restrict__ Q,
    const unsigned short* __restrict__ Kg,
    const unsigned short* __restrict__ Vt,
    const float* __restrict__ biases,
    unsigned short* __restrict__ Og) {
  __shared__ unsigned short sK[2][64 * 64];
  __shared__ unsigned short sV[2][64 * 64];   // [d][kv], 16B-chunk XOR-swizzled
  __shared__ float sBias[1024];

  const int bx = blockIdx.x;
  const int bh = bx & 127, qt = bx >> 7;      // XCD swizzle: same bh -> same XCD
  const int h = bh & 15, b = bh >> 4;
  const int tid = threadIdx.x, w = tid >> 6, lane = tid & 63;
  const int l15 = lane & 15, quad = lane >> 4;

  const size_t bhs = (size_t)(b * 16 + h);
  const unsigned short* qbase = Q + (bhs * 1024 + (size_t)qt * 128) * 64;
  const unsigned short* kbase = Kg + bhs * 1024 * 64;
  const unsigned short* vbase = Vt + bhs * 64 * 1024;

  for (int t = tid; t < 1024; t += 256) sBias[t] = biases[h * 1024 + t] * L2E;

  const int sr0 = w * 16 + (lane >> 3);
  const int sc8 = lane & 7;
  const int sw0 = sc8 ^ (lane >> 3);

  gl_lds16(kbase + (size_t)sr0 * 64 + sw0 * 8,        &sK[0][(w * 16) * 64]);
  gl_lds16(kbase + (size_t)(sr0 + 8) * 64 + sw0 * 8,  &sK[0][(w * 16 + 8) * 64]);
  gl_lds16(vbase + (size_t)sr0 * 1024 + sw0 * 8,      &sV[0][(w * 16) * 64]);
  gl_lds16(vbase + (size_t)(sr0 + 8) * 1024 + sw0 * 8,&sV[0][(w * 16 + 8) * 64]);

  bf16x8 qf[2][2];
#pragma unroll
  for (int qb = 0; qb < 2; qb++)
#pragma unroll
    for (int kd = 0; kd < 2; kd++)
      qf[qb][kd] = *(const bf16x8*)(qbase + (w * 32 + qb * 16 + l15) * 64 + kd * 32 + quad * 8);

  const int qg0 = qt * 128 + w * 32;
  // qi = (qg0 + qb*16 + l15)>>5 = qt*4 + w  (qb*16+l15 <= 31) -> WAVE-UNIFORM
  const int qiw = __builtin_amdgcn_readfirstlane(qt * 4 + w);
  // iteration-invariant dj offsets: dj[qb][kp][r] = |qb*16+l15 - kp*16 - quad*4 - r|
  int djo[2][2][4];
#pragma unroll
  for (int qb = 0; qb < 2; qb++)
#pragma unroll
    for (int kp = 0; kp < 2; kp++)
#pragma unroll
      for (int r = 0; r < 4; r++)
        djo[qb][kp][r] = abs(qb * 16 + l15 - kp * 16 - quad * 4 - r);

  const f32x4 fz = {0.f, 0.f, 0.f, 0.f};
  f32x4 of[2][4], osum[2];
#pragma unroll
  for (int i = 0; i < 2; i++) {
    osum[i] = fz;
#pragma unroll
    for (int j = 0; j < 4; j++) of[i][j] = fz;
  }
  const bf16x4 vones = {(short)0x3F80, (short)0x3F80, (short)0x3F80, (short)0x3F80};

  int buf = 0;
  for (int j0 = 0; j0 < 1024; j0 += 64) {
    vm_drain();
    __syncthreads();
    if (j0 + 64 < 1024) {
      int nb = buf ^ 1, jn = j0 + 64;
      gl_lds16(kbase + (size_t)(jn + sr0) * 64 + sw0 * 8,       &sK[nb][(w * 16) * 64]);
      gl_lds16(kbase + (size_t)(jn + sr0 + 8) * 64 + sw0 * 8,   &sK[nb][(w * 16 + 8) * 64]);
      gl_lds16(vbase + (size_t)sr0 * 1024 + jn + sw0 * 8,       &sV[nb][(w * 16) * 64]);
      gl_lds16(vbase + (size_t)(sr0 + 8) * 1024 + jn + sw0 * 8, &sV[nb][(w * 16 + 8) * 64]);
    }
    const unsigned short* K_ = sK[buf];
    const unsigned short* V_ = sV[buf];
    const int j5 = j0 >> 5;
    const int dh = qiw - j5;
    const float* bA = sBias + (abs(dh) << 5);       // kvb 0,1 (kvi = j5)
    const float* bB = sBias + (abs(dh - 1) << 5);   // kvb 2,3 (kvi = j5+1)

#pragma unroll
    for (int kvb = 0; kvb < 4; kvb++) {
      bf16x8 kf0 = *(const bf16x8*)&K_[(kvb * 16 + l15) * 64 + ((quad ^ (l15 & 7)) << 3)];
      bf16x8 kf1 = *(const bf16x8*)&K_[(kvb * 16 + l15) * 64 + (((4 + quad) ^ (l15 & 7)) << 3)];
      bf16x4 vf[4];
#pragma unroll
      for (int nt = 0; nt < 4; nt++) {
        int d = nt * 16 + l15;
        vf[nt] = *(const bf16x4*)&V_[d * 64 + (((kvb * 2 + (quad >> 1)) ^ (l15 & 7)) << 3) + (quad & 1) * 4];
      }
      const float* bp = (kvb < 2) ? bA : bB;
      const int kp = kvb & 1;
#pragma unroll
      for (int qb = 0; qb < 2; qb++) {
        f32x4 s4 = __builtin_amdgcn_mfma_f32_16x16x32_bf16(kf0, qf[qb][0], fz, 0, 0, 0);
        s4 = __builtin_amdgcn_mfma_f32_16x16x32_bf16(kf1, qf[qb][1], s4, 0, 0, 0);
        float p0 = __builtin_amdgcn_exp2f(s4.x + bp[djo[qb][kp][0]]);
        float p1 = __builtin_amdgcn_exp2f(s4.y + bp[djo[qb][kp][1]]);
        float p2 = __builtin_amdgcn_exp2f(s4.z + bp[djo[qb][kp][2]]);
        float p3 = __builtin_amdgcn_exp2f(s4.w + bp[djo[qb][kp][3]]);
        union { unsigned int u[2]; bf16x4 v; } pk;
        pk.u[0] = f2bf2(p0, p1);
        pk.u[1] = f2bf2(p2, p3);
#pragma unroll
        for (int nt = 0; nt < 4; nt++)
          of[qb][nt] = __builtin_amdgcn_mfma_f32_16x16x16bf16_1k(pk.v, vf[nt], of[qb][nt], 0, 0, 0);
        osum[qb] = __builtin_amdgcn_mfma_f32_16x16x16bf16_1k(pk.v, vones, osum[qb], 0, 0, 0);
      }
    }
    buf ^= 1;
  }

  const int kvq = quad * 4;
#pragma unroll
  for (int qb = 0; qb < 2; qb++)
#pragma unroll
    for (int r = 0; r < 4; r++) {
      float inv = __builtin_amdgcn_rcpf(osum[qb][r]);   // same C-layout row as of
      int n = qg0 + qb * 16 + kvq + r;
      size_t orow = ((size_t)b * 1024 + n) * 1024 + h * 64;
#pragma unroll
      for (int nt = 0; nt < 4; nt++)
        Og[orow + nt * 16 + l15] = f2bf(of[qb][nt][r] * inv);
    }
}

// ---------------- out-proj GEMM: [8192,1024] x [1024,1024]^T + b ----------------
__global__ __launch_bounds__(256, 4) void gemm_out_k(
    const unsigned short* __restrict__ A,
    const unsigned short* __restrict__ Bm,
    const float* __restrict__ bias,
    float* __restrict__ out) {
  __shared__ unsigned short sA[2][128 * 32];
  __shared__ unsigned short sB[2][128 * 32];
  const int K = 1024;
  const int tid = threadIdx.x;
  const int w = tid >> 6, lane = tid & 63;
  const int l15 = lane & 15, quad = lane >> 4;
  const int wm = (w >> 1) * 64, wn = (w & 1) * 64;
  const int tm = blockIdx.y, tn = blockIdx.x;

  const unsigned short* Ab = A + (size_t)(tm * 128) * K;
  const unsigned short* Bb = Bm + (size_t)(tn * 128) * K;

  const int srow = w * 32 + (lane >> 2);
  const int scol = (((lane & 3) ^ ((lane >> 3) & 3))) * 8;
  const int rsw = (l15 >> 1) & 3;

  const f32x4 fz = {0.f, 0.f, 0.f, 0.f};
  f32x4 acc[4][4];
#pragma unroll
  for (int i = 0; i < 4; i++)
#pragma unroll
    for (int j = 0; j < 4; j++) acc[i][j] = fz;

  gl_lds16(Ab + (size_t)srow * K + scol,        &sA[0][(w * 32) * 32]);
  gl_lds16(Ab + (size_t)(srow + 16) * K + scol, &sA[0][(w * 32 + 16) * 32]);
  gl_lds16(Bb + (size_t)srow * K + scol,        &sB[0][(w * 32) * 32]);
  gl_lds16(Bb + (size_t)(srow + 16) * K + scol, &sB[0][(w * 32 + 16) * 32]);

  int buf = 0;
  for (int k0 = 0; k0 < K; k0 += 32) {
    vm_drain();
    __syncthreads();
    if (k0 + 32 < K) {
      int nb = buf ^ 1, kn = k0 + 32;
      gl_lds16(Ab + (size_t)srow * K + kn + scol,        &sA[nb][(w * 32) * 32]);
      gl_lds16(Ab + (size_t)(srow + 16) * K + kn + scol, &sA[nb][(w * 32 + 16) * 32]);
      gl_lds16(Bb + (size_t)srow * K + kn + scol,        &sB[nb][(w * 32) * 32]);
      gl_lds16(Bb + (size_t)(srow + 16) * K + kn + scol, &sB[nb][(w * 32 + 16) * 32]);
    }
    bf16x8 af[4], bfr[4];
#pragma unroll
    for (int mt = 0; mt < 4; mt++)
      af[mt] = *(const bf16x8*)&sA[buf][(wm + mt * 16 + l15) * 32 + ((quad ^ rsw) << 3)];
#pragma unroll
    for (int nt = 0; nt < 4; nt++)
      bfr[nt] = *(const bf16x8*)&sB[buf][(wn + nt * 16 + l15) * 32 + ((quad ^ rsw) << 3)];
#pragma unroll
    for (int mt = 0; mt < 4; mt++)
#pragma unroll
      for (int nt = 0; nt < 4; nt++)
        acc[mt][nt] = __builtin_amdgcn_mfma_f32_16x16x32_bf16(af[mt], bfr[nt], acc[mt][nt], 0, 0, 0);
    buf ^= 1;
  }

  const int m0 = tm * 128 + wm, c0 = tn * 128 + wn;
#pragma unroll
  for (int mt = 0; mt < 4; mt++)
#pragma unroll
    for (int nt = 0; nt < 4; nt++)
#pragma unroll
      for (int r = 0; r < 4; r++) {
        int m = m0 + mt * 16 + quad * 4 + r;
        int c = c0 + nt * 16 + l15;
        out[(size_t)m * 1024 + c] = acc[mt][nt][r] + bias[c];
      }
}

extern "C" void kernel_launch(void* const* d_in, const int* in_sizes, int n_in,
                              void* d_out, int out_size, void* d_ws, size_t ws_size,
                              hipStream_t stream) {
  const float* x    = (const float*)d_in[0];
  const float* Wqkv = (const float*)d_in[1];
  const float* ab   = (const float*)d_in[2];
  // d_in[3] (bias_idxs) unused: idx == |n/32-m/32|*32 + |n%32-m%32| analytically
  const float* Wout = (const float*)d_in[4];
  const float* bout = (const float*)d_in[5];
  float* out = (float*)d_out;

  char* ws = (char*)d_ws;
  unsigned short* xb  = (unsigned short*)(ws);                    // 16 MB
  unsigned short* wqb = (unsigned short*)(ws + 16777216);         // 6 MB
  unsigned short* wob = (unsigned short*)(ws + 23068672);         // 2 MB
  unsigned short* qw  = (unsigned short*)(ws + 25165824);         // 16 MB
  unsigned short* kw  = (unsigned short*)(ws + 41943040);         // 16 MB
  unsigned short* vw  = (unsigned short*)(ws + 58720256);         // 16 MB (vT)
  unsigned short* ow  = (unsigned short*)(ws + 75497472);         // 16 MB

  cast3_kernel<<<1536, 256, 0, stream>>>(x, Wqkv, Wout, xb, wqb, wob);
  gemm_qkv<<<dim3(24, 64), 256, 0, stream>>>(xb, wqb, qw, kw, vw);
  attn_kernel<<<1024, 256, 0, stream>>>(qw, kw, vw, ab, ow);
  gemm_out_k<<<dim3(8, 64), 256, 0, stream>>>(ow, wob, bout, out);
}

// Round 7
// 271.651 us; speedup vs baseline: 3.4132x; 3.4132x over previous
//
#include <hip/hip_runtime.h>

typedef __attribute__((ext_vector_type(8))) short bf16x8;
typedef __attribute__((ext_vector_type(4))) short bf16x4;
typedef __attribute__((ext_vector_type(4))) float f32x4;

#define L2E 1.44269504088896340736f
#define QSCL 0.18033688011112042f   // 0.125 * log2(e)

__device__ inline unsigned short f2bf(float f) {
  union { float f; unsigned int u; } x; x.f = f;
  return (unsigned short)((x.u + 0x8000u) >> 16);
}
__device__ inline unsigned int f2bf2(float a, float b) {
  union { float f; unsigned int u; } xa, xb;
  xa.f = a; xb.f = b;
  return ((xa.u + 0x8000u) >> 16) | (((xb.u + 0x8000u) & 0xFFFF0000u));
}

__device__ inline void gl_lds16(const void* g, void* l) {
  __builtin_amdgcn_global_load_lds((const __attribute__((address_space(1))) void*)g,
                                   (__attribute__((address_space(3))) void*)l,
                                   16, 0, 0);
}

// Explicit LDS-DMA drain before each barrier: the compiler's alias-based
// vmcnt tracking dropped the wait in R4 (warm-replay race). Keep always.
__device__ inline void vm_drain() {
  asm volatile("s_waitcnt vmcnt(0)" ::: "memory");
}

// ---------------- fused cast fp32 -> bf16 (x, W_qkv, W_out) ----------------
#define N4_X  2097152   // 8192*1024/4
#define N4_WQ 786432    // 3072*1024/4
#define N4_WO 262144    // 1024*1024/4
__global__ void cast3_kernel(const float* __restrict__ x,
                             const float* __restrict__ wq,
                             const float* __restrict__ wo,
                             unsigned short* __restrict__ xb,
                             unsigned short* __restrict__ wqb,
                             unsigned short* __restrict__ wob) {
  int i = blockIdx.x * blockDim.x + threadIdx.x;
  int st = gridDim.x * blockDim.x;
  for (; i < N4_X + N4_WQ + N4_WO; i += st) {
    const float* src; unsigned short* dst; int j;
    if (i < N4_X)            { src = x;  dst = xb;  j = i; }
    else if (i < N4_X + N4_WQ){ src = wq; dst = wqb; j = i - N4_X; }
    else                     { src = wo; dst = wob; j = i - N4_X - N4_WQ; }
    float4 v = reinterpret_cast<const float4*>(src)[j];
    ushort4 o;
    o.x = f2bf(v.x); o.y = f2bf(v.y); o.z = f2bf(v.z); o.w = f2bf(v.w);
    reinterpret_cast<ushort4*>(dst)[j] = o;
  }
}

// ---------------- QKV GEMM: [8192,1024] x [3072,1024]^T ----------------
// Compile-time MODE (runtime branch caused acc[4][4] scratch spill in R6:
// VGPR 88->64, WRITE_SIZE 2.4 GB, 748 us. NEVER branch around MFMA loops.)
// MODE 0: q/k (tn 0..15), swapped-operand MFMA -> C^T, lane holds 4 consecutive
//         features at fixed token -> direct b64 stores to [b,h,n,64].
// MODE 1: v (tn 16..23), normal MFMA, lane holds 4 consecutive tokens at fixed
//         feature -> direct b64 stores to vT [b,h,64,n].
template <int MODE>
__global__ __launch_bounds__(256, 4) void gemm_qkv_t(
    const unsigned short* __restrict__ A,
    const unsigned short* __restrict__ Bm,
    unsigned short* __restrict__ qo,
    unsigned short* __restrict__ ko,
    unsigned short* __restrict__ vo) {
  __shared__ unsigned short sA[2][128 * 32];
  __shared__ unsigned short sB[2][128 * 32];
  const int K = 1024;
  const int tid = threadIdx.x;
  const int w = tid >> 6, lane = tid & 63;
  const int l15 = lane & 15, quad = lane >> 4;
  const int wm = (w >> 1) * 64, wn = (w & 1) * 64;
  const int tm = blockIdx.y;
  const int tn = (MODE == 0) ? blockIdx.x : blockIdx.x + 16;

  const unsigned short* Ab = A + (size_t)(tm * 128) * K;
  const unsigned short* Bb = Bm + (size_t)(tn * 128) * K;

  const int srow = w * 32 + (lane >> 2);
  const int scol = (((lane & 3) ^ ((lane >> 3) & 3))) * 8;   // swizzled content chunk
  const int rsw = (l15 >> 1) & 3;                            // read-side swizzle key

  const f32x4 fz = {0.f, 0.f, 0.f, 0.f};
  f32x4 acc[4][4];
#pragma unroll
  for (int i = 0; i < 4; i++)
#pragma unroll
    for (int j = 0; j < 4; j++) acc[i][j] = fz;

  gl_lds16(Ab + (size_t)srow * K + scol,        &sA[0][(w * 32) * 32]);
  gl_lds16(Ab + (size_t)(srow + 16) * K + scol, &sA[0][(w * 32 + 16) * 32]);
  gl_lds16(Bb + (size_t)srow * K + scol,        &sB[0][(w * 32) * 32]);
  gl_lds16(Bb + (size_t)(srow + 16) * K + scol, &sB[0][(w * 32 + 16) * 32]);

  int buf = 0;
  for (int k0 = 0; k0 < K; k0 += 32) {
    vm_drain();
    __syncthreads();
    if (k0 + 32 < K) {
      int nb = buf ^ 1, kn = k0 + 32;
      gl_lds16(Ab + (size_t)srow * K + kn + scol,        &sA[nb][(w * 32) * 32]);
      gl_lds16(Ab + (size_t)(srow + 16) * K + kn + scol, &sA[nb][(w * 32 + 16) * 32]);
      gl_lds16(Bb + (size_t)srow * K + kn + scol,        &sB[nb][(w * 32) * 32]);
      gl_lds16(Bb + (size_t)(srow + 16) * K + kn + scol, &sB[nb][(w * 32 + 16) * 32]);
    }
    bf16x8 af[4], bfr[4];
#pragma unroll
    for (int mt = 0; mt < 4; mt++)
      af[mt] = *(const bf16x8*)&sA[buf][(wm + mt * 16 + l15) * 32 + ((quad ^ rsw) << 3)];
#pragma unroll
    for (int nt = 0; nt < 4; nt++)
      bfr[nt] = *(const bf16x8*)&sB[buf][(wn + nt * 16 + l15) * 32 + ((quad ^ rsw) << 3)];
#pragma unroll
    for (int mt = 0; mt < 4; mt++)
#pragma unroll
      for (int nt = 0; nt < 4; nt++) {
        if (MODE == 0)
          acc[mt][nt] = __builtin_amdgcn_mfma_f32_16x16x32_bf16(bfr[nt], af[mt], acc[mt][nt], 0, 0, 0);
        else
          acc[mt][nt] = __builtin_amdgcn_mfma_f32_16x16x32_bf16(af[mt], bfr[nt], acc[mt][nt], 0, 0, 0);
      }
    buf ^= 1;
  }

  const int m0 = tm * 128;
  const int bb = m0 >> 10, n0 = m0 & 1023;
  const int cbase = (tn * 128) & 1023;

  if (MODE == 0) {
    const int which = tn >> 3;                 // 0:q 1:k
    const float scl = (which == 0) ? QSCL : 1.0f;
    unsigned short* dst = (which == 0) ? qo : ko;
#pragma unroll
    for (int mt = 0; mt < 4; mt++) {
      int tok = n0 + wm + mt * 16 + l15;
#pragma unroll
      for (int nt = 0; nt < 4; nt++) {
        int c = cbase + wn + nt * 16 + quad * 4;
        int hh = c >> 6, d0 = c & 63;
        uint2 val;
        val.x = f2bf2(acc[mt][nt][0] * scl, acc[mt][nt][1] * scl);
        val.y = f2bf2(acc[mt][nt][2] * scl, acc[mt][nt][3] * scl);
        *(uint2*)&dst[(((size_t)bb * 16 + hh) * 1024 + tok) * 64 + d0] = val;
      }
    }
  } else {
#pragma unroll
    for (int mt = 0; mt < 4; mt++) {
      int tok = n0 + wm + mt * 16 + quad * 4;
#pragma unroll
      for (int nt = 0; nt < 4; nt++) {
        int c = cbase + wn + nt * 16 + l15;
        int hh = c >> 6, dd = c & 63;
        uint2 val;
        val.x = f2bf2(acc[mt][nt][0], acc[mt][nt][1]);
        val.y = f2bf2(acc[mt][nt][2], acc[mt][nt][3]);
        *(uint2*)&vo[(((size_t)bb * 16 + hh) * 64 + dd) * 1024 + tok] = val;
      }
    }
  }
}

// ---------------- flash attention: S^T, register PV, scalar-di bias, MFMA rsum ----
__global__ __launch_bounds__(256, 4) void attn_kernel(
    const unsigned short* __restrict__ Q,
    const unsigned short* __restrict__ Kg,
    const unsigned short* __restrict__ Vt,
    const float* __restrict__ biases,
    unsigned short* __restrict__ Og) {
  __shared__ unsigned short sK[2][64 * 64];
  __shared__ unsigned short sV[2][64 * 64];   // [d][kv], 16B-chunk XOR-swizzled
  __shared__ float sBias[1024];

  const int bx = blockIdx.x;
  const int bh = bx & 127, qt = bx >> 7;      // XCD swizzle: same bh -> same XCD
  const int h = bh & 15, b = bh >> 4;
  const int tid = threadIdx.x, w = tid >> 6, lane = tid & 63;
  const int l15 = lane & 15, quad = lane >> 4;

  const size_t bhs = (size_t)(b * 16 + h);
  const unsigned short* qbase = Q + (bhs * 1024 + (size_t)qt * 128) * 64;
  const unsigned short* kbase = Kg + bhs * 1024 * 64;
  const unsigned short* vbase = Vt + bhs * 64 * 1024;

  for (int t = tid; t < 1024; t += 256) sBias[t] = biases[h * 1024 + t] * L2E;

  const int sr0 = w * 16 + (lane >> 3);
  const int sc8 = lane & 7;
  const int sw0 = sc8 ^ (lane >> 3);

  gl_lds16(kbase + (size_t)sr0 * 64 + sw0 * 8,        &sK[0][(w * 16) * 64]);
  gl_lds16(kbase + (size_t)(sr0 + 8) * 64 + sw0 * 8,  &sK[0][(w * 16 + 8) * 64]);
  gl_lds16(vbase + (size_t)sr0 * 1024 + sw0 * 8,      &sV[0][(w * 16) * 64]);
  gl_lds16(vbase + (size_t)(sr0 + 8) * 1024 + sw0 * 8,&sV[0][(w * 16 + 8) * 64]);

  bf16x8 qf[2][2];
#pragma unroll
  for (int qb = 0; qb < 2; qb++)
#pragma unroll
    for (int kd = 0; kd < 2; kd++)
      qf[qb][kd] = *(const bf16x8*)(qbase + (w * 32 + qb * 16 + l15) * 64 + kd * 32 + quad * 8);

  const int qg0 = qt * 128 + w * 32;
  // qi = (qg0 + qb*16 + l15)>>5 = qt*4 + w  (qb*16+l15 <= 31) -> WAVE-UNIFORM
  const int qiw = __builtin_amdgcn_readfirstlane(qt * 4 + w);
  // iteration-invariant dj offsets: dj[qb][kp][r] = |qb*16+l15 - kp*16 - quad*4 - r|
  int djo[2][2][4];
#pragma unroll
  for (int qb = 0; qb < 2; qb++)
#pragma unroll
    for (int kp = 0; kp < 2; kp++)
#pragma unroll
      for (int r = 0; r < 4; r++)
        djo[qb][kp][r] = abs(qb * 16 + l15 - kp * 16 - quad * 4 - r);

  const f32x4 fz = {0.f, 0.f, 0.f, 0.f};
  f32x4 of[2][4], osum[2];
#pragma unroll
  for (int i = 0; i < 2; i++) {
    osum[i] = fz;
#pragma unroll
    for (int j = 0; j < 4; j++) of[i][j] = fz;
  }
  const bf16x4 vones = {(short)0x3F80, (short)0x3F80, (short)0x3F80, (short)0x3F80};

  int buf = 0;
  for (int j0 = 0; j0 < 1024; j0 += 64) {
    vm_drain();
    __syncthreads();
    if (j0 + 64 < 1024) {
      int nb = buf ^ 1, jn = j0 + 64;
      gl_lds16(kbase + (size_t)(jn + sr0) * 64 + sw0 * 8,       &sK[nb][(w * 16) * 64]);
      gl_lds16(kbase + (size_t)(jn + sr0 + 8) * 64 + sw0 * 8,   &sK[nb][(w * 16 + 8) * 64]);
      gl_lds16(vbase + (size_t)sr0 * 1024 + jn + sw0 * 8,       &sV[nb][(w * 16) * 64]);
      gl_lds16(vbase + (size_t)(sr0 + 8) * 1024 + jn + sw0 * 8, &sV[nb][(w * 16 + 8) * 64]);
    }
    const unsigned short* K_ = sK[buf];
    const unsigned short* V_ = sV[buf];
    const int j5 = j0 >> 5;
    const int dh = qiw - j5;
    const float* bA = sBias + (abs(dh) << 5);       // kvb 0,1 (kvi = j5)
    const float* bB = sBias + (abs(dh - 1) << 5);   // kvb 2,3 (kvi = j5+1)

#pragma unroll
    for (int kvb = 0; kvb < 4; kvb++) {
      bf16x8 kf0 = *(const bf16x8*)&K_[(kvb * 16 + l15) * 64 + ((quad ^ (l15 & 7)) << 3)];
      bf16x8 kf1 = *(const bf16x8*)&K_[(kvb * 16 + l15) * 64 + (((4 + quad) ^ (l15 & 7)) << 3)];
      bf16x4 vf[4];
#pragma unroll
      for (int nt = 0; nt < 4; nt++) {
        int d = nt * 16 + l15;
        vf[nt] = *(const bf16x4*)&V_[d * 64 + (((kvb * 2 + (quad >> 1)) ^ (l15 & 7)) << 3) + (quad & 1) * 4];
      }
      const float* bp = (kvb < 2) ? bA : bB;
      const int kp = kvb & 1;
#pragma unroll
      for (int qb = 0; qb < 2; qb++) {
        f32x4 s4 = __builtin_amdgcn_mfma_f32_16x16x32_bf16(kf0, qf[qb][0], fz, 0, 0, 0);
        s4 = __builtin_amdgcn_mfma_f32_16x16x32_bf16(kf1, qf[qb][1], s4, 0, 0, 0);
        float p0 = __builtin_amdgcn_exp2f(s4.x + bp[djo[qb][kp][0]]);
        float p1 = __builtin_amdgcn_exp2f(s4.y + bp[djo[qb][kp][1]]);
        float p2 = __builtin_amdgcn_exp2f(s4.z + bp[djo[qb][kp][2]]);
        float p3 = __builtin_amdgcn_exp2f(s4.w + bp[djo[qb][kp][3]]);
        union { unsigned int u[2]; bf16x4 v; } pk;
        pk.u[0] = f2bf2(p0, p1);
        pk.u[1] = f2bf2(p2, p3);
#pragma unroll
        for (int nt = 0; nt < 4; nt++)
          of[qb][nt] = __builtin_amdgcn_mfma_f32_16x16x16bf16_1k(pk.v, vf[nt], of[qb][nt], 0, 0, 0);
        osum[qb] = __builtin_amdgcn_mfma_f32_16x16x16bf16_1k(pk.v, vones, osum[qb], 0, 0, 0);
      }
    }
    buf ^= 1;
  }

  const int kvq = quad * 4;
#pragma unroll
  for (int qb = 0; qb < 2; qb++)
#pragma unroll
    for (int r = 0; r < 4; r++) {
      float inv = __builtin_amdgcn_rcpf(osum[qb][r]);   // same C-layout row as of
      int n = qg0 + qb * 16 + kvq + r;
      size_t orow = ((size_t)b * 1024 + n) * 1024 + h * 64;
#pragma unroll
      for (int nt = 0; nt < 4; nt++)
        Og[orow + nt * 16 + l15] = f2bf(of[qb][nt][r] * inv);
    }
}

// ---------------- out-proj GEMM: [8192,1024] x [1024,1024]^T + b ----------------
__global__ __launch_bounds__(256, 4) void gemm_out_k(
    const unsigned short* __restrict__ A,
    const unsigned short* __restrict__ Bm,
    const float* __restrict__ bias,
    float* __restrict__ out) {
  __shared__ unsigned short sA[2][128 * 32];
  __shared__ unsigned short sB[2][128 * 32];
  const int K = 1024;
  const int tid = threadIdx.x;
  const int w = tid >> 6, lane = tid & 63;
  const int l15 = lane & 15, quad = lane >> 4;
  const int wm = (w >> 1) * 64, wn = (w & 1) * 64;
  const int tm = blockIdx.y, tn = blockIdx.x;

  const unsigned short* Ab = A + (size_t)(tm * 128) * K;
  const unsigned short* Bb = Bm + (size_t)(tn * 128) * K;

  const int srow = w * 32 + (lane >> 2);
  const int scol = (((lane & 3) ^ ((lane >> 3) & 3))) * 8;
  const int rsw = (l15 >> 1) & 3;

  const f32x4 fz = {0.f, 0.f, 0.f, 0.f};
  f32x4 acc[4][4];
#pragma unroll
  for (int i = 0; i < 4; i++)
#pragma unroll
    for (int j = 0; j < 4; j++) acc[i][j] = fz;

  gl_lds16(Ab + (size_t)srow * K + scol,        &sA[0][(w * 32) * 32]);
  gl_lds16(Ab + (size_t)(srow + 16) * K + scol, &sA[0][(w * 32 + 16) * 32]);
  gl_lds16(Bb + (size_t)srow * K + scol,        &sB[0][(w * 32) * 32]);
  gl_lds16(Bb + (size_t)(srow + 16) * K + scol, &sB[0][(w * 32 + 16) * 32]);

  int buf = 0;
  for (int k0 = 0; k0 < K; k0 += 32) {
    vm_drain();
    __syncthreads();
    if (k0 + 32 < K) {
      int nb = buf ^ 1, kn = k0 + 32;
      gl_lds16(Ab + (size_t)srow * K + kn + scol,        &sA[nb][(w * 32) * 32]);
      gl_lds16(Ab + (size_t)(srow + 16) * K + kn + scol, &sA[nb][(w * 32 + 16) * 32]);
      gl_lds16(Bb + (size_t)srow * K + kn + scol,        &sB[nb][(w * 32) * 32]);
      gl_lds16(Bb + (size_t)(srow + 16) * K + kn + scol, &sB[nb][(w * 32 + 16) * 32]);
    }
    bf16x8 af[4], bfr[4];
#pragma unroll
    for (int mt = 0; mt < 4; mt++)
      af[mt] = *(const bf16x8*)&sA[buf][(wm + mt * 16 + l15) * 32 + ((quad ^ rsw) << 3)];
#pragma unroll
    for (int nt = 0; nt < 4; nt++)
      bfr[nt] = *(const bf16x8*)&sB[buf][(wn + nt * 16 + l15) * 32 + ((quad ^ rsw) << 3)];
#pragma unroll
    for (int mt = 0; mt < 4; mt++)
#pragma unroll
      for (int nt = 0; nt < 4; nt++)
        acc[mt][nt] = __builtin_amdgcn_mfma_f32_16x16x32_bf16(af[mt], bfr[nt], acc[mt][nt], 0, 0, 0);
    buf ^= 1;
  }

  const int m0 = tm * 128 + wm, c0 = tn * 128 + wn;
#pragma unroll
  for (int mt = 0; mt < 4; mt++)
#pragma unroll
    for (int nt = 0; nt < 4; nt++)
#pragma unroll
      for (int r = 0; r < 4; r++) {
        int m = m0 + mt * 16 + quad * 4 + r;
        int c = c0 + nt * 16 + l15;
        out[(size_t)m * 1024 + c] = acc[mt][nt][r] + bias[c];
      }
}

extern "C" void kernel_launch(void* const* d_in, const int* in_sizes, int n_in,
                              void* d_out, int out_size, void* d_ws, size_t ws_size,
                              hipStream_t stream) {
  const float* x    = (const float*)d_in[0];
  const float* Wqkv = (const float*)d_in[1];
  const float* ab   = (const float*)d_in[2];
  // d_in[3] (bias_idxs) unused: idx == |n/32-m/32|*32 + |n%32-m%32| analytically
  const float* Wout = (const float*)d_in[4];
  const float* bout = (const float*)d_in[5];
  float* out = (float*)d_out;

  char* ws = (char*)d_ws;
  unsigned short* xb  = (unsigned short*)(ws);                    // 16 MB
  unsigned short* wqb = (unsigned short*)(ws + 16777216);         // 6 MB
  unsigned short* wob = (unsigned short*)(ws + 23068672);         // 2 MB
  unsigned short* qw  = (unsigned short*)(ws + 25165824);         // 16 MB
  unsigned short* kw  = (unsigned short*)(ws + 41943040);         // 16 MB
  unsigned short* vw  = (unsigned short*)(ws + 58720256);         // 16 MB (vT)
  unsigned short* ow  = (unsigned short*)(ws + 75497472);         // 16 MB

  cast3_kernel<<<1536, 256, 0, stream>>>(x, Wqkv, Wout, xb, wqb, wob);
  gemm_qkv_t<0><<<dim3(16, 64), 256, 0, stream>>>(xb, wqb, qw, kw, vw);
  gemm_qkv_t<1><<<dim3(8, 64), 256, 0, stream>>>(xb, wqb, qw, kw, vw);
  attn_kernel<<<1024, 256, 0, stream>>>(qw, kw, vw, ab, ow);
  gemm_out_k<<<dim3(8, 64), 256, 0, stream>>>(ow, wob, bout, out);
}

// Round 8
// 264.830 us; speedup vs baseline: 3.5011x; 1.0258x over previous
//
#include <hip/hip_runtime.h>

typedef __attribute__((ext_vector_type(8))) short bf16x8;
typedef __attribute__((ext_vector_type(4))) short bf16x4;
typedef __attribute__((ext_vector_type(4))) float f32x4;

#define L2E 1.44269504088896340736f
#define QSCL 0.18033688011112042f   // 0.125 * log2(e)

__device__ inline unsigned short f2bf(float f) {
  union { float f; unsigned int u; } x; x.f = f;
  return (unsigned short)((x.u + 0x8000u) >> 16);
}
__device__ inline unsigned int f2bf2(float a, float b) {
  union { float f; unsigned int u; } xa, xb;
  xa.f = a; xb.f = b;
  return ((xa.u + 0x8000u) >> 16) | (((xb.u + 0x8000u) & 0xFFFF0000u));
}
// HW packed f32->bf16x2 (gfx950 v_cvt_pk_bf16_f32), compile-safe fallback.
__device__ inline unsigned int pk_bf16(float a, float b) {
#if __has_builtin(__builtin_amdgcn_cvt_pk_bf16_f32)
  typedef __attribute__((ext_vector_type(2))) __bf16 bfv2;
  union { bfv2 v; unsigned int u; } x;
  x.v = __builtin_amdgcn_cvt_pk_bf16_f32(a, b);
  return x.u;
#else
  return f2bf2(a, b);
#endif
}

__device__ inline void gl_lds16(const void* g, void* l) {
  __builtin_amdgcn_global_load_lds((const __attribute__((address_space(1))) void*)g,
                                   (__attribute__((address_space(3))) void*)l,
                                   16, 0, 0);
}

// Explicit LDS-DMA drain before each barrier: the compiler's alias-based
// vmcnt tracking dropped the wait in R4 (warm-replay race). Keep always.
__device__ inline void vm_drain() {
  asm volatile("s_waitcnt vmcnt(0)" ::: "memory");
}

// ---------------- fused cast fp32 -> bf16 (x, W_qkv, W_out) ----------------
#define N4_X  2097152   // 8192*1024/4
#define N4_WQ 786432    // 3072*1024/4
#define N4_WO 262144    // 1024*1024/4
__global__ void cast3_kernel(const float* __restrict__ x,
                             const float* __restrict__ wq,
                             const float* __restrict__ wo,
                             unsigned short* __restrict__ xb,
                             unsigned short* __restrict__ wqb,
                             unsigned short* __restrict__ wob) {
  int i = blockIdx.x * blockDim.x + threadIdx.x;
  int st = gridDim.x * blockDim.x;
  for (; i < N4_X + N4_WQ + N4_WO; i += st) {
    const float* src; unsigned short* dst; int j;
    if (i < N4_X)            { src = x;  dst = xb;  j = i; }
    else if (i < N4_X + N4_WQ){ src = wq; dst = wqb; j = i - N4_X; }
    else                     { src = wo; dst = wob; j = i - N4_X - N4_WQ; }
    float4 v = reinterpret_cast<const float4*>(src)[j];
    ushort4 o;
    o.x = f2bf(v.x); o.y = f2bf(v.y); o.z = f2bf(v.z); o.w = f2bf(v.w);
    reinterpret_cast<ushort4*>(dst)[j] = o;
  }
}

// ---------------- QKV GEMM: [8192,1024] x [3072,1024]^T ----------------
// Compile-time MODE (runtime branch caused acc[4][4] scratch spill in R6:
// VGPR 88->64, WRITE_SIZE 2.4 GB, 748 us. NEVER branch around MFMA loops.)
// MODE 0: q/k (tn 0..15), swapped-operand MFMA -> C^T, lane holds 4 consecutive
//         features at fixed token -> direct b64 stores to [b,h,n,64].
// MODE 1: v (tn 16..23), normal MFMA, lane holds 4 consecutive tokens at fixed
//         feature -> direct b64 stores to vT [b,h,64,n].
template <int MODE>
__global__ __launch_bounds__(256, 4) void gemm_qkv_t(
    const unsigned short* __restrict__ A,
    const unsigned short* __restrict__ Bm,
    unsigned short* __restrict__ qo,
    unsigned short* __restrict__ ko,
    unsigned short* __restrict__ vo) {
  __shared__ unsigned short sA[2][128 * 32];
  __shared__ unsigned short sB[2][128 * 32];
  const int K = 1024;
  const int tid = threadIdx.x;
  const int w = tid >> 6, lane = tid & 63;
  const int l15 = lane & 15, quad = lane >> 4;
  const int wm = (w >> 1) * 64, wn = (w & 1) * 64;
  const int tm = blockIdx.y;
  const int tn = (MODE == 0) ? blockIdx.x : blockIdx.x + 16;

  const unsigned short* Ab = A + (size_t)(tm * 128) * K;
  const unsigned short* Bb = Bm + (size_t)(tn * 128) * K;

  const int srow = w * 32 + (lane >> 2);
  const int scol = (((lane & 3) ^ ((lane >> 3) & 3))) * 8;   // swizzled content chunk
  const int rsw = (l15 >> 1) & 3;                            // read-side swizzle key

  const f32x4 fz = {0.f, 0.f, 0.f, 0.f};
  f32x4 acc[4][4];
#pragma unroll
  for (int i = 0; i < 4; i++)
#pragma unroll
    for (int j = 0; j < 4; j++) acc[i][j] = fz;

  gl_lds16(Ab + (size_t)srow * K + scol,        &sA[0][(w * 32) * 32]);
  gl_lds16(Ab + (size_t)(srow + 16) * K + scol, &sA[0][(w * 32 + 16) * 32]);
  gl_lds16(Bb + (size_t)srow * K + scol,        &sB[0][(w * 32) * 32]);
  gl_lds16(Bb + (size_t)(srow + 16) * K + scol, &sB[0][(w * 32 + 16) * 32]);

  int buf = 0;
  for (int k0 = 0; k0 < K; k0 += 32) {
    vm_drain();
    __syncthreads();
    if (k0 + 32 < K) {
      int nb = buf ^ 1, kn = k0 + 32;
      gl_lds16(Ab + (size_t)srow * K + kn + scol,        &sA[nb][(w * 32) * 32]);
      gl_lds16(Ab + (size_t)(srow + 16) * K + kn + scol, &sA[nb][(w * 32 + 16) * 32]);
      gl_lds16(Bb + (size_t)srow * K + kn + scol,        &sB[nb][(w * 32) * 32]);
      gl_lds16(Bb + (size_t)(srow + 16) * K + kn + scol, &sB[nb][(w * 32 + 16) * 32]);
    }
    bf16x8 af[4], bfr[4];
#pragma unroll
    for (int mt = 0; mt < 4; mt++)
      af[mt] = *(const bf16x8*)&sA[buf][(wm + mt * 16 + l15) * 32 + ((quad ^ rsw) << 3)];
#pragma unroll
    for (int nt = 0; nt < 4; nt++)
      bfr[nt] = *(const bf16x8*)&sB[buf][(wn + nt * 16 + l15) * 32 + ((quad ^ rsw) << 3)];
#pragma unroll
    for (int mt = 0; mt < 4; mt++)
#pragma unroll
      for (int nt = 0; nt < 4; nt++) {
        if (MODE == 0)
          acc[mt][nt] = __builtin_amdgcn_mfma_f32_16x16x32_bf16(bfr[nt], af[mt], acc[mt][nt], 0, 0, 0);
        else
          acc[mt][nt] = __builtin_amdgcn_mfma_f32_16x16x32_bf16(af[mt], bfr[nt], acc[mt][nt], 0, 0, 0);
      }
    buf ^= 1;
  }

  const int m0 = tm * 128;
  const int bb = m0 >> 10, n0 = m0 & 1023;
  const int cbase = (tn * 128) & 1023;

  if (MODE == 0) {
    const int which = tn >> 3;                 // 0:q 1:k
    const float scl = (which == 0) ? QSCL : 1.0f;
    unsigned short* dst = (which == 0) ? qo : ko;
#pragma unroll
    for (int mt = 0; mt < 4; mt++) {
      int tok = n0 + wm + mt * 16 + l15;
#pragma unroll
      for (int nt = 0; nt < 4; nt++) {
        int c = cbase + wn + nt * 16 + quad * 4;
        int hh = c >> 6, d0 = c & 63;
        uint2 val;
        val.x = f2bf2(acc[mt][nt][0] * scl, acc[mt][nt][1] * scl);
        val.y = f2bf2(acc[mt][nt][2] * scl, acc[mt][nt][3] * scl);
        *(uint2*)&dst[(((size_t)bb * 16 + hh) * 1024 + tok) * 64 + d0] = val;
      }
    }
  } else {
#pragma unroll
    for (int mt = 0; mt < 4; mt++) {
      int tok = n0 + wm + mt * 16 + quad * 4;
#pragma unroll
      for (int nt = 0; nt < 4; nt++) {
        int c = cbase + wn + nt * 16 + l15;
        int hh = c >> 6, dd = c & 63;
        uint2 val;
        val.x = f2bf2(acc[mt][nt][0], acc[mt][nt][1]);
        val.y = f2bf2(acc[mt][nt][2], acc[mt][nt][3]);
        *(uint2*)&vo[(((size_t)bb * 16 + hh) * 64 + dd) * 1024 + tok] = val;
      }
    }
  }
}

// ---------------- flash attention: S^T, register PV, reflected-bias, MFMA rsum ----
// Bias table is reflected (no per-element abs in the index): sBias2[di][31+t],
// t = qj-kvj in -31..31, row stride 63 floats. The 4 bias values per (kvb,qb)
// are then CONSECUTIVE LDS addresses -> compiler merges to 2x ds_read2_b32
// (was 4x ds_read_b32 through abs-folded indices). Bias was the largest LDS
// instruction class (32/tile vs 24 for K+V) -> now 16/tile.
__global__ __launch_bounds__(256, 4) void attn_kernel(
    const unsigned short* __restrict__ Q,
    const unsigned short* __restrict__ Kg,
    const unsigned short* __restrict__ Vt,
    const float* __restrict__ biases,
    unsigned short* __restrict__ Og) {
  __shared__ unsigned short sK[2][64 * 64];
  __shared__ unsigned short sV[2][64 * 64];   // [d][kv], 16B-chunk XOR-swizzled
  __shared__ float sBias2[32 * 63];           // reflected: [di][31 + (qj-kvj)]

  const int bx = blockIdx.x;
  const int bh = bx & 127, qt = bx >> 7;      // XCD swizzle: same bh -> same XCD
  const int h = bh & 15, b = bh >> 4;
  const int tid = threadIdx.x, w = tid >> 6, lane = tid & 63;
  const int l15 = lane & 15, quad = lane >> 4;

  const size_t bhs = (size_t)(b * 16 + h);
  const unsigned short* qbase = Q + (bhs * 1024 + (size_t)qt * 128) * 64;
  const unsigned short* kbase = Kg + bhs * 1024 * 64;
  const unsigned short* vbase = Vt + bhs * 64 * 1024;

  for (int t = tid; t < 2048; t += 256) {
    int d = t >> 6, u = t & 63;
    if (u < 63) {
      int dj = u - 31; dj = dj < 0 ? -dj : dj;
      sBias2[d * 63 + u] = biases[h * 1024 + d * 32 + dj] * L2E;
    }
  }

  const int sr0 = w * 16 + (lane >> 3);
  const int sc8 = lane & 7;
  const int sw0 = sc8 ^ (lane >> 3);

  gl_lds16(kbase + (size_t)sr0 * 64 + sw0 * 8,        &sK[0][(w * 16) * 64]);
  gl_lds16(kbase + (size_t)(sr0 + 8) * 64 + sw0 * 8,  &sK[0][(w * 16 + 8) * 64]);
  gl_lds16(vbase + (size_t)sr0 * 1024 + sw0 * 8,      &sV[0][(w * 16) * 64]);
  gl_lds16(vbase + (size_t)(sr0 + 8) * 1024 + sw0 * 8,&sV[0][(w * 16 + 8) * 64]);

  bf16x8 qf[2][2];
#pragma unroll
  for (int qb = 0; qb < 2; qb++)
#pragma unroll
    for (int kd = 0; kd < 2; kd++)
      qf[qb][kd] = *(const bf16x8*)(qbase + (w * 32 + qb * 16 + l15) * 64 + kd * 32 + quad * 8);

  const int qg0 = qt * 128 + w * 32;
  // qi = (qg0 + qb*16 + l15)>>5 = qt*4 + w  (qb*16+l15 <= 31) -> WAVE-UNIFORM
  const int qiw = __builtin_amdgcn_readfirstlane(qt * 4 + w);
  // signed column offset (no abs — table is reflected): c = qj - kvj_base
  int cc[2][2];
#pragma unroll
  for (int qb = 0; qb < 2; qb++)
#pragma unroll
    for (int kp = 0; kp < 2; kp++)
      cc[qb][kp] = qb * 16 + l15 - kp * 16 - quad * 4;

  const f32x4 fz = {0.f, 0.f, 0.f, 0.f};
  f32x4 of[2][4], osum[2];
#pragma unroll
  for (int i = 0; i < 2; i++) {
    osum[i] = fz;
#pragma unroll
    for (int j = 0; j < 4; j++) of[i][j] = fz;
  }
  const bf16x4 vones = {(short)0x3F80, (short)0x3F80, (short)0x3F80, (short)0x3F80};

  int buf = 0;
  for (int j0 = 0; j0 < 1024; j0 += 64) {
    vm_drain();
    __syncthreads();
    if (j0 + 64 < 1024) {
      int nb = buf ^ 1, jn = j0 + 64;
      gl_lds16(kbase + (size_t)(jn + sr0) * 64 + sw0 * 8,       &sK[nb][(w * 16) * 64]);
      gl_lds16(kbase + (size_t)(jn + sr0 + 8) * 64 + sw0 * 8,   &sK[nb][(w * 16 + 8) * 64]);
      gl_lds16(vbase + (size_t)sr0 * 1024 + jn + sw0 * 8,       &sV[nb][(w * 16) * 64]);
      gl_lds16(vbase + (size_t)(sr0 + 8) * 1024 + jn + sw0 * 8, &sV[nb][(w * 16 + 8) * 64]);
    }
    const unsigned short* K_ = sK[buf];
    const unsigned short* V_ = sV[buf];
    const int j5 = j0 >> 5;
    const int dh = qiw - j5;
    const float* bA = sBias2 + abs(dh) * 63 + 31;       // kvb 0,1 (kvi = j5)
    const float* bB = sBias2 + abs(dh - 1) * 63 + 31;   // kvb 2,3 (kvi = j5+1)

#pragma unroll
    for (int kvb = 0; kvb < 4; kvb++) {
      bf16x8 kf0 = *(const bf16x8*)&K_[(kvb * 16 + l15) * 64 + ((quad ^ (l15 & 7)) << 3)];
      bf16x8 kf1 = *(const bf16x8*)&K_[(kvb * 16 + l15) * 64 + (((4 + quad) ^ (l15 & 7)) << 3)];
      bf16x4 vf[4];
#pragma unroll
      for (int nt = 0; nt < 4; nt++) {
        int d = nt * 16 + l15;
        vf[nt] = *(const bf16x4*)&V_[d * 64 + (((kvb * 2 + (quad >> 1)) ^ (l15 & 7)) << 3) + (quad & 1) * 4];
      }
      const float* bp = (kvb < 2) ? bA : bB;
      const int kp = kvb & 1;
#pragma unroll
      for (int qb = 0; qb < 2; qb++) {
        f32x4 s4 = __builtin_amdgcn_mfma_f32_16x16x32_bf16(kf0, qf[qb][0], fz, 0, 0, 0);
        s4 = __builtin_amdgcn_mfma_f32_16x16x32_bf16(kf1, qf[qb][1], s4, 0, 0, 0);
        const float* bq = bp + cc[qb][kp];   // bq[-r] = bias for kv=kvjb+r
        float p0 = __builtin_amdgcn_exp2f(s4.x + bq[0]);
        float p1 = __builtin_amdgcn_exp2f(s4.y + bq[-1]);
        float p2 = __builtin_amdgcn_exp2f(s4.z + bq[-2]);
        float p3 = __builtin_amdgcn_exp2f(s4.w + bq[-3]);
        union { unsigned int u[2]; bf16x4 v; } pk;
        pk.u[0] = pk_bf16(p0, p1);
        pk.u[1] = pk_bf16(p2, p3);
#pragma unroll
        for (int nt = 0; nt < 4; nt++)
          of[qb][nt] = __builtin_amdgcn_mfma_f32_16x16x16bf16_1k(pk.v, vf[nt], of[qb][nt], 0, 0, 0);
        osum[qb] = __builtin_amdgcn_mfma_f32_16x16x16bf16_1k(pk.v, vones, osum[qb], 0, 0, 0);
      }
    }
    buf ^= 1;
  }

  const int kvq = quad * 4;
#pragma unroll
  for (int qb = 0; qb < 2; qb++)
#pragma unroll
    for (int r = 0; r < 4; r++) {
      float inv = __builtin_amdgcn_rcpf(osum[qb][r]);   // same C-layout row as of
      int n = qg0 + qb * 16 + kvq + r;
      size_t orow = ((size_t)b * 1024 + n) * 1024 + h * 64;
#pragma unroll
      for (int nt = 0; nt < 4; nt++)
        Og[orow + nt * 16 + l15] = f2bf(of[qb][nt][r] * inv);
    }
}

// ---------------- out-proj GEMM: [8192,1024] x [1024,1024]^T + b ----------------
__global__ __launch_bounds__(256, 4) void gemm_out_k(
    const unsigned short* __restrict__ A,
    const unsigned short* __restrict__ Bm,
    const float* __restrict__ bias,
    float* __restrict__ out) {
  __shared__ unsigned short sA[2][128 * 32];
  __shared__ unsigned short sB[2][128 * 32];
  const int K = 1024;
  const int tid = threadIdx.x;
  const int w = tid >> 6, lane = tid & 63;
  const int l15 = lane & 15, quad = lane >> 4;
  const int wm = (w >> 1) * 64, wn = (w & 1) * 64;
  const int tm = blockIdx.y, tn = blockIdx.x;

  const unsigned short* Ab = A + (size_t)(tm * 128) * K;
  const unsigned short* Bb = Bm + (size_t)(tn * 128) * K;

  const int srow = w * 32 + (lane >> 2);
  const int scol = (((lane & 3) ^ ((lane >> 3) & 3))) * 8;
  const int rsw = (l15 >> 1) & 3;

  const f32x4 fz = {0.f, 0.f, 0.f, 0.f};
  f32x4 acc[4][4];
#pragma unroll
  for (int i = 0; i < 4; i++)
#pragma unroll
    for (int j = 0; j < 4; j++) acc[i][j] = fz;

  gl_lds16(Ab + (size_t)srow * K + scol,        &sA[0][(w * 32) * 32]);
  gl_lds16(Ab + (size_t)(srow + 16) * K + scol, &sA[0][(w * 32 + 16) * 32]);
  gl_lds16(Bb + (size_t)srow * K + scol,        &sB[0][(w * 32) * 32]);
  gl_lds16(Bb + (size_t)(srow + 16) * K + scol, &sB[0][(w * 32 + 16) * 32]);

  int buf = 0;
  for (int k0 = 0; k0 < K; k0 += 32) {
    vm_drain();
    __syncthreads();
    if (k0 + 32 < K) {
      int nb = buf ^ 1, kn = k0 + 32;
      gl_lds16(Ab + (size_t)srow * K + kn + scol,        &sA[nb][(w * 32) * 32]);
      gl_lds16(Ab + (size_t)(srow + 16) * K + kn + scol, &sA[nb][(w * 32 + 16) * 32]);
      gl_lds16(Bb + (size_t)srow * K + kn + scol,        &sB[nb][(w * 32) * 32]);
      gl_lds16(Bb + (size_t)(srow + 16) * K + kn + scol, &sB[nb][(w * 32 + 16) * 32]);
    }
    bf16x8 af[4], bfr[4];
#pragma unroll
    for (int mt = 0; mt < 4; mt++)
      af[mt] = *(const bf16x8*)&sA[buf][(wm + mt * 16 + l15) * 32 + ((quad ^ rsw) << 3)];
#pragma unroll
    for (int nt = 0; nt < 4; nt++)
      bfr[nt] = *(const bf16x8*)&sB[buf][(wn + nt * 16 + l15) * 32 + ((quad ^ rsw) << 3)];
#pragma unroll
    for (int mt = 0; mt < 4; mt++)
#pragma unroll
      for (int nt = 0; nt < 4; nt++)
        acc[mt][nt] = __builtin_amdgcn_mfma_f32_16x16x32_bf16(af[mt], bfr[nt], acc[mt][nt], 0, 0, 0);
    buf ^= 1;
  }

  const int m0 = tm * 128 + wm, c0 = tn * 128 + wn;
#pragma unroll
  for (int mt = 0; mt < 4; mt++)
#pragma unroll
    for (int nt = 0; nt < 4; nt++)
#pragma unroll
      for (int r = 0; r < 4; r++) {
        int m = m0 + mt * 16 + quad * 4 + r;
        int c = c0 + nt * 16 + l15;
        out[(size_t)m * 1024 + c] = acc[mt][nt][r] + bias[c];
      }
}

extern "C" void kernel_launch(void* const* d_in, const int* in_sizes, int n_in,
                              void* d_out, int out_size, void* d_ws, size_t ws_size,
                              hipStream_t stream) {
  const float* x    = (const float*)d_in[0];
  const float* Wqkv = (const float*)d_in[1];
  const float* ab   = (const float*)d_in[2];
  // d_in[3] (bias_idxs) unused: idx == |n/32-m/32|*32 + |n%32-m%32| analytically
  const float* Wout = (const float*)d_in[4];
  const float* bout = (const float*)d_in[5];
  float* out = (float*)d_out;

  char* ws = (char*)d_ws;
  unsigned short* xb  = (unsigned short*)(ws);                    // 16 MB
  unsigned short* wqb = (unsigned short*)(ws + 16777216);         // 6 MB
  unsigned short* wob = (unsigned short*)(ws + 23068672);         // 2 MB
  unsigned short* qw  = (unsigned short*)(ws + 25165824);         // 16 MB
  unsigned short* kw  = (unsigned short*)(ws + 41943040);         // 16 MB
  unsigned short* vw  = (unsigned short*)(ws + 58720256);         // 16 MB (vT)
  unsigned short* ow  = (unsigned short*)(ws + 75497472);         // 16 MB

  cast3_kernel<<<1536, 256, 0, stream>>>(x, Wqkv, Wout, xb, wqb, wob);
  gemm_qkv_t<0><<<dim3(16, 64), 256, 0, stream>>>(xb, wqb, qw, kw, vw);
  gemm_qkv_t<1><<<dim3(8, 64), 256, 0, stream>>>(xb, wqb, qw, kw, vw);
  attn_kernel<<<1024, 256, 0, stream>>>(qw, kw, vw, ab, ow);
  gemm_out_k<<<dim3(8, 64), 256, 0, stream>>>(ow, wob, bout, out);
}

// Round 9
// 252.716 us; speedup vs baseline: 3.6689x; 1.0479x over previous
//
#include <hip/hip_runtime.h>

typedef __attribute__((ext_vector_type(8))) short bf16x8;
typedef __attribute__((ext_vector_type(4))) short bf16x4;
typedef __attribute__((ext_vector_type(4))) float f32x4;

#define L2E 1.44269504088896340736f
#define QSCL 0.18033688011112042f   // 0.125 * log2(e)

__device__ inline unsigned short f2bf(float f) {
  union { float f; unsigned int u; } x; x.f = f;
  return (unsigned short)((x.u + 0x8000u) >> 16);
}
__device__ inline unsigned int f2bf2(float a, float b) {
  union { float f; unsigned int u; } xa, xb;
  xa.f = a; xb.f = b;
  return ((xa.u + 0x8000u) >> 16) | (((xb.u + 0x8000u) & 0xFFFF0000u));
}
// HW packed f32->bf16x2 (gfx950 v_cvt_pk_bf16_f32), compile-safe fallback.
__device__ inline unsigned int pk_bf16(float a, float b) {
#if __has_builtin(__builtin_amdgcn_cvt_pk_bf16_f32)
  typedef __attribute__((ext_vector_type(2))) __bf16 bfv2;
  union { bfv2 v; unsigned int u; } x;
  x.v = __builtin_amdgcn_cvt_pk_bf16_f32(a, b);
  return x.u;
#else
  return f2bf2(a, b);
#endif
}

__device__ inline void gl_lds16(const void* g, void* l) {
  __builtin_amdgcn_global_load_lds((const __attribute__((address_space(1))) void*)g,
                                   (__attribute__((address_space(3))) void*)l,
                                   16, 0, 0);
}

// Explicit LDS-DMA drain before each barrier: the compiler's alias-based
// vmcnt tracking dropped the wait in R4 (warm-replay race). Keep always.
__device__ inline void vm_drain() {
  asm volatile("s_waitcnt vmcnt(0)" ::: "memory");
}

// ---------------- fused cast fp32 -> bf16 (x, W_qkv, W_out) ----------------
#define N4_X  2097152   // 8192*1024/4
#define N4_WQ 786432    // 3072*1024/4
#define N4_WO 262144    // 1024*1024/4
__global__ void cast3_kernel(const float* __restrict__ x,
                             const float* __restrict__ wq,
                             const float* __restrict__ wo,
                             unsigned short* __restrict__ xb,
                             unsigned short* __restrict__ wqb,
                             unsigned short* __restrict__ wob) {
  int i = blockIdx.x * blockDim.x + threadIdx.x;
  int st = gridDim.x * blockDim.x;
  for (; i < N4_X + N4_WQ + N4_WO; i += st) {
    const float* src; unsigned short* dst; int j;
    if (i < N4_X)            { src = x;  dst = xb;  j = i; }
    else if (i < N4_X + N4_WQ){ src = wq; dst = wqb; j = i - N4_X; }
    else                     { src = wo; dst = wob; j = i - N4_X - N4_WQ; }
    float4 v = reinterpret_cast<const float4*>(src)[j];
    ushort4 o;
    o.x = f2bf(v.x); o.y = f2bf(v.y); o.z = f2bf(v.z); o.w = f2bf(v.w);
    reinterpret_cast<ushort4*>(dst)[j] = o;
  }
}

// ---------------- QKV GEMM: [8192,1024] x [3072,1024]^T ----------------
// Single kernel, branch OUTSIDE the K-loop (uniform per block) into a
// compile-time-MODE body. (R6 lesson: a runtime branch INSIDE the MFMA loop
// spilled acc[4][4] to scratch — VGPR 88->64, WRITE_SIZE 2.4 GB, 748 us.)
// MODE 0: q/k (tn 0..15), swapped-operand MFMA -> C^T, lane holds 4 consecutive
//         features at fixed token -> direct b64 stores to [b,h,n,64].
// MODE 1: v (tn 16..23), normal MFMA, lane holds 4 consecutive tokens at fixed
//         feature -> direct b64 stores to vT [b,h,64,n].
template <int MODE>
__device__ __forceinline__ void gemm_qkv_body(
    unsigned short* __restrict__ sA,   // [2][128*32] flattened
    unsigned short* __restrict__ sB,
    const unsigned short* __restrict__ A,
    const unsigned short* __restrict__ Bm,
    unsigned short* __restrict__ qo,
    unsigned short* __restrict__ ko,
    unsigned short* __restrict__ vo) {
  const int K = 1024;
  const int tid = threadIdx.x;
  const int w = tid >> 6, lane = tid & 63;
  const int l15 = lane & 15, quad = lane >> 4;
  const int wm = (w >> 1) * 64, wn = (w & 1) * 64;
  const int tm = blockIdx.y;
  const int tn = blockIdx.x;          // 0..15 (MODE 0) / 16..23 (MODE 1)

  const unsigned short* Ab = A + (size_t)(tm * 128) * K;
  const unsigned short* Bb = Bm + (size_t)(tn * 128) * K;

  const int srow = w * 32 + (lane >> 2);
  const int scol = (((lane & 3) ^ ((lane >> 3) & 3))) * 8;   // swizzled content chunk
  const int rsw = (l15 >> 1) & 3;                            // read-side swizzle key

  const f32x4 fz = {0.f, 0.f, 0.f, 0.f};
  f32x4 acc[4][4];
#pragma unroll
  for (int i = 0; i < 4; i++)
#pragma unroll
    for (int j = 0; j < 4; j++) acc[i][j] = fz;

  gl_lds16(Ab + (size_t)srow * K + scol,        &sA[(w * 32) * 32]);
  gl_lds16(Ab + (size_t)(srow + 16) * K + scol, &sA[(w * 32 + 16) * 32]);
  gl_lds16(Bb + (size_t)srow * K + scol,        &sB[(w * 32) * 32]);
  gl_lds16(Bb + (size_t)(srow + 16) * K + scol, &sB[(w * 32 + 16) * 32]);

  int buf = 0;
  for (int k0 = 0; k0 < K; k0 += 32) {
    vm_drain();
    __syncthreads();
    if (k0 + 32 < K) {
      int nb = buf ^ 1, kn = k0 + 32;
      gl_lds16(Ab + (size_t)srow * K + kn + scol,        &sA[nb * 4096 + (w * 32) * 32]);
      gl_lds16(Ab + (size_t)(srow + 16) * K + kn + scol, &sA[nb * 4096 + (w * 32 + 16) * 32]);
      gl_lds16(Bb + (size_t)srow * K + kn + scol,        &sB[nb * 4096 + (w * 32) * 32]);
      gl_lds16(Bb + (size_t)(srow + 16) * K + kn + scol, &sB[nb * 4096 + (w * 32 + 16) * 32]);
    }
    bf16x8 af[4], bfr[4];
#pragma unroll
    for (int mt = 0; mt < 4; mt++)
      af[mt] = *(const bf16x8*)&sA[buf * 4096 + (wm + mt * 16 + l15) * 32 + ((quad ^ rsw) << 3)];
#pragma unroll
    for (int nt = 0; nt < 4; nt++)
      bfr[nt] = *(const bf16x8*)&sB[buf * 4096 + (wn + nt * 16 + l15) * 32 + ((quad ^ rsw) << 3)];
#pragma unroll
    for (int mt = 0; mt < 4; mt++)
#pragma unroll
      for (int nt = 0; nt < 4; nt++) {
        if (MODE == 0)
          acc[mt][nt] = __builtin_amdgcn_mfma_f32_16x16x32_bf16(bfr[nt], af[mt], acc[mt][nt], 0, 0, 0);
        else
          acc[mt][nt] = __builtin_amdgcn_mfma_f32_16x16x32_bf16(af[mt], bfr[nt], acc[mt][nt], 0, 0, 0);
      }
    buf ^= 1;
  }

  const int m0 = tm * 128;
  const int bb = m0 >> 10, n0 = m0 & 1023;
  const int cbase = (tn * 128) & 1023;

  if (MODE == 0) {
    const int which = tn >> 3;                 // 0:q 1:k
    const float scl = (which == 0) ? QSCL : 1.0f;
    unsigned short* dst = (which == 0) ? qo : ko;
#pragma unroll
    for (int mt = 0; mt < 4; mt++) {
      int tok = n0 + wm + mt * 16 + l15;
#pragma unroll
      for (int nt = 0; nt < 4; nt++) {
        int c = cbase + wn + nt * 16 + quad * 4;
        int hh = c >> 6, d0 = c & 63;
        uint2 val;
        val.x = f2bf2(acc[mt][nt][0] * scl, acc[mt][nt][1] * scl);
        val.y = f2bf2(acc[mt][nt][2] * scl, acc[mt][nt][3] * scl);
        *(uint2*)&dst[(((size_t)bb * 16 + hh) * 1024 + tok) * 64 + d0] = val;
      }
    }
  } else {
#pragma unroll
    for (int mt = 0; mt < 4; mt++) {
      int tok = n0 + wm + mt * 16 + quad * 4;
#pragma unroll
      for (int nt = 0; nt < 4; nt++) {
        int c = cbase + wn + nt * 16 + l15;
        int hh = c >> 6, dd = c & 63;
        uint2 val;
        val.x = f2bf2(acc[mt][nt][0], acc[mt][nt][1]);
        val.y = f2bf2(acc[mt][nt][2], acc[mt][nt][3]);
        *(uint2*)&vo[(((size_t)bb * 16 + hh) * 64 + dd) * 1024 + tok] = val;
      }
    }
  }
}

__global__ __launch_bounds__(256, 4) void gemm_qkv(
    const unsigned short* __restrict__ A,
    const unsigned short* __restrict__ Bm,
    unsigned short* __restrict__ qo,
    unsigned short* __restrict__ ko,
    unsigned short* __restrict__ vo) {
  __shared__ unsigned short sA[2][128 * 32];
  __shared__ unsigned short sB[2][128 * 32];
  if (blockIdx.x < 16) gemm_qkv_body<0>(&sA[0][0], &sB[0][0], A, Bm, qo, ko, vo);
  else                 gemm_qkv_body<1>(&sA[0][0], &sB[0][0], A, Bm, qo, ko, vo);
}

// ---------------- flash attention: S^T, register PV, reflected-bias, MFMA rsum ----
// qb=4: each wave covers 64 q-rows (block 256, grid 512). K/V LDS fragment
// reads are qb-independent -> per-CU K/V LDS traffic halves vs qb=2.
// Bias row index stays wave-uniform per qb: qi = qt*8 + w*2 + (qb>>1).
__global__ __launch_bounds__(256, 2) void attn_kernel(
    const unsigned short* __restrict__ Q,
    const unsigned short* __restrict__ Kg,
    const unsigned short* __restrict__ Vt,
    const float* __restrict__ biases,
    unsigned short* __restrict__ Og) {
  __shared__ unsigned short sK[2][64 * 64];
  __shared__ unsigned short sV[2][64 * 64];   // [d][kv], 16B-chunk XOR-swizzled
  __shared__ float sBias2[32 * 63];           // reflected: [di][31 + (qj-kvj)]

  const int bx = blockIdx.x;
  const int bh = bx & 127, qt = bx >> 7;      // qt 0..3; same bh -> same XCD
  const int h = bh & 15, b = bh >> 4;
  const int tid = threadIdx.x, w = tid >> 6, lane = tid & 63;
  const int l15 = lane & 15, quad = lane >> 4;

  const size_t bhs = (size_t)(b * 16 + h);
  const unsigned short* qbase = Q + (bhs * 1024 + (size_t)qt * 256) * 64;
  const unsigned short* kbase = Kg + bhs * 1024 * 64;
  const unsigned short* vbase = Vt + bhs * 64 * 1024;

  for (int t = tid; t < 2048; t += 256) {
    int d = t >> 6, u = t & 63;
    if (u < 63) {
      int dj = u - 31; dj = dj < 0 ? -dj : dj;
      sBias2[d * 63 + u] = biases[h * 1024 + d * 32 + dj] * L2E;
    }
  }

  const int sr0 = w * 16 + (lane >> 3);
  const int sc8 = lane & 7;
  const int sw0 = sc8 ^ (lane >> 3);

  gl_lds16(kbase + (size_t)sr0 * 64 + sw0 * 8,        &sK[0][(w * 16) * 64]);
  gl_lds16(kbase + (size_t)(sr0 + 8) * 64 + sw0 * 8,  &sK[0][(w * 16 + 8) * 64]);
  gl_lds16(vbase + (size_t)sr0 * 1024 + sw0 * 8,      &sV[0][(w * 16) * 64]);
  gl_lds16(vbase + (size_t)(sr0 + 8) * 1024 + sw0 * 8,&sV[0][(w * 16 + 8) * 64]);

  bf16x8 qf[4][2];
#pragma unroll
  for (int qb = 0; qb < 4; qb++)
#pragma unroll
    for (int kd = 0; kd < 2; kd++)
      qf[qb][kd] = *(const bf16x8*)(qbase + (w * 64 + qb * 16 + l15) * 64 + kd * 32 + quad * 8);

  const int qg0 = qt * 256 + w * 64;
  const int qtw = __builtin_amdgcn_readfirstlane(qt * 8 + w * 2);
  // signed column offset (table is reflected): depends only on (qb&1, kp)
  int cc2[2][2];
#pragma unroll
  for (int qh = 0; qh < 2; qh++)
#pragma unroll
    for (int kp = 0; kp < 2; kp++)
      cc2[qh][kp] = qh * 16 + l15 - kp * 16 - quad * 4;

  const f32x4 fz = {0.f, 0.f, 0.f, 0.f};
  f32x4 of[4][4], osum[4];
#pragma unroll
  for (int i = 0; i < 4; i++) {
    osum[i] = fz;
#pragma unroll
    for (int j = 0; j < 4; j++) of[i][j] = fz;
  }
  const bf16x4 vones = {(short)0x3F80, (short)0x3F80, (short)0x3F80, (short)0x3F80};

  int buf = 0;
  for (int j0 = 0; j0 < 1024; j0 += 64) {
    vm_drain();
    __syncthreads();
    if (j0 + 64 < 1024) {
      int nb = buf ^ 1, jn = j0 + 64;
      gl_lds16(kbase + (size_t)(jn + sr0) * 64 + sw0 * 8,       &sK[nb][(w * 16) * 64]);
      gl_lds16(kbase + (size_t)(jn + sr0 + 8) * 64 + sw0 * 8,   &sK[nb][(w * 16 + 8) * 64]);
      gl_lds16(vbase + (size_t)sr0 * 1024 + jn + sw0 * 8,       &sV[nb][(w * 16) * 64]);
      gl_lds16(vbase + (size_t)(sr0 + 8) * 1024 + jn + sw0 * 8, &sV[nb][(w * 16 + 8) * 64]);
    }
    const unsigned short* K_ = sK[buf];
    const unsigned short* V_ = sV[buf];
    const int j5 = j0 >> 5;
    const int dh = qtw - j5;                  // qi(qb) = qtw + (qb>>1)
    const float* b0 = sBias2 + abs(dh) * 63 + 31;       // (qb>>1) == (kvb>>1)
    const float* bM = sBias2 + abs(dh - 1) * 63 + 31;   // qb<2, kvb>=2
    const float* bP = sBias2 + abs(dh + 1) * 63 + 31;   // qb>=2, kvb<2

#pragma unroll
    for (int kvb = 0; kvb < 4; kvb++) {
      bf16x8 kf0 = *(const bf16x8*)&K_[(kvb * 16 + l15) * 64 + ((quad ^ (l15 & 7)) << 3)];
      bf16x8 kf1 = *(const bf16x8*)&K_[(kvb * 16 + l15) * 64 + (((4 + quad) ^ (l15 & 7)) << 3)];
      bf16x4 vf[4];
#pragma unroll
      for (int nt = 0; nt < 4; nt++) {
        int d = nt * 16 + l15;
        vf[nt] = *(const bf16x4*)&V_[d * 64 + (((kvb * 2 + (quad >> 1)) ^ (l15 & 7)) << 3) + (quad & 1) * 4];
      }
      const int kp = kvb & 1;
#pragma unroll
      for (int qb = 0; qb < 4; qb++) {
        f32x4 s4 = __builtin_amdgcn_mfma_f32_16x16x32_bf16(kf0, qf[qb][0], fz, 0, 0, 0);
        s4 = __builtin_amdgcn_mfma_f32_16x16x32_bf16(kf1, qf[qb][1], s4, 0, 0, 0);
        const float* bp = (qb < 2) ? ((kvb < 2) ? b0 : bM)
                                   : ((kvb < 2) ? bP : b0);
        const float* bq = bp + cc2[qb & 1][kp];   // bq[-r] = bias for kv=kvjb+r
        float p0 = __builtin_amdgcn_exp2f(s4.x + bq[0]);
        float p1 = __builtin_amdgcn_exp2f(s4.y + bq[-1]);
        float p2 = __builtin_amdgcn_exp2f(s4.z + bq[-2]);
        float p3 = __builtin_amdgcn_exp2f(s4.w + bq[-3]);
        union { unsigned int u[2]; bf16x4 v; } pk;
        pk.u[0] = pk_bf16(p0, p1);
        pk.u[1] = pk_bf16(p2, p3);
#pragma unroll
        for (int nt = 0; nt < 4; nt++)
          of[qb][nt] = __builtin_amdgcn_mfma_f32_16x16x16bf16_1k(pk.v, vf[nt], of[qb][nt], 0, 0, 0);
        osum[qb] = __builtin_amdgcn_mfma_f32_16x16x16bf16_1k(pk.v, vones, osum[qb], 0, 0, 0);
      }
    }
    buf ^= 1;
  }

  const int kvq = quad * 4;
#pragma unroll
  for (int qb = 0; qb < 4; qb++)
#pragma unroll
    for (int r = 0; r < 4; r++) {
      float inv = __builtin_amdgcn_rcpf(osum[qb][r]);   // same C-layout row as of
      int n = qg0 + qb * 16 + kvq + r;
      size_t orow = ((size_t)b * 1024 + n) * 1024 + h * 64;
#pragma unroll
      for (int nt = 0; nt < 4; nt++)
        Og[orow + nt * 16 + l15] = f2bf(of[qb][nt][r] * inv);
    }
}

// ---------------- out-proj GEMM: [8192,1024] x [1024,1024]^T + b ----------------
__global__ __launch_bounds__(256, 4) void gemm_out_k(
    const unsigned short* __restrict__ A,
    const unsigned short* __restrict__ Bm,
    const float* __restrict__ bias,
    float* __restrict__ out) {
  __shared__ unsigned short sA[2][128 * 32];
  __shared__ unsigned short sB[2][128 * 32];
  const int K = 1024;
  const int tid = threadIdx.x;
  const int w = tid >> 6, lane = tid & 63;
  const int l15 = lane & 15, quad = lane >> 4;
  const int wm = (w >> 1) * 64, wn = (w & 1) * 64;
  const int tm = blockIdx.y, tn = blockIdx.x;

  const unsigned short* Ab = A + (size_t)(tm * 128) * K;
  const unsigned short* Bb = Bm + (size_t)(tn * 128) * K;

  const int srow = w * 32 + (lane >> 2);
  const int scol = (((lane & 3) ^ ((lane >> 3) & 3))) * 8;
  const int rsw = (l15 >> 1) & 3;

  const f32x4 fz = {0.f, 0.f, 0.f, 0.f};
  f32x4 acc[4][4];
#pragma unroll
  for (int i = 0; i < 4; i++)
#pragma unroll
    for (int j = 0; j < 4; j++) acc[i][j] = fz;

  gl_lds16(Ab + (size_t)srow * K + scol,        &sA[0][(w * 32) * 32]);
  gl_lds16(Ab + (size_t)(srow + 16) * K + scol, &sA[0][(w * 32 + 16) * 32]);
  gl_lds16(Bb + (size_t)srow * K + scol,        &sB[0][(w * 32) * 32]);
  gl_lds16(Bb + (size_t)(srow + 16) * K + scol, &sB[0][(w * 32 + 16) * 32]);

  int buf = 0;
  for (int k0 = 0; k0 < K; k0 += 32) {
    vm_drain();
    __syncthreads();
    if (k0 + 32 < K) {
      int nb = buf ^ 1, kn = k0 + 32;
      gl_lds16(Ab + (size_t)srow * K + kn + scol,        &sA[nb][(w * 32) * 32]);
      gl_lds16(Ab + (size_t)(srow + 16) * K + kn + scol, &sA[nb][(w * 32 + 16) * 32]);
      gl_lds16(Bb + (size_t)srow * K + kn + scol,        &sB[nb][(w * 32) * 32]);
      gl_lds16(Bb + (size_t)(srow + 16) * K + kn + scol, &sB[nb][(w * 32 + 16) * 32]);
    }
    bf16x8 af[4], bfr[4];
#pragma unroll
    for (int mt = 0; mt < 4; mt++)
      af[mt] = *(const bf16x8*)&sA[buf][(wm + mt * 16 + l15) * 32 + ((quad ^ rsw) << 3)];
#pragma unroll
    for (int nt = 0; nt < 4; nt++)
      bfr[nt] = *(const bf16x8*)&sB[buf][(wn + nt * 16 + l15) * 32 + ((quad ^ rsw) << 3)];
#pragma unroll
    for (int mt = 0; mt < 4; mt++)
#pragma unroll
      for (int nt = 0; nt < 4; nt++)
        acc[mt][nt] = __builtin_amdgcn_mfma_f32_16x16x32_bf16(af[mt], bfr[nt], acc[mt][nt], 0, 0, 0);
    buf ^= 1;
  }

  const int m0 = tm * 128 + wm, c0 = tn * 128 + wn;
#pragma unroll
  for (int mt = 0; mt < 4; mt++)
#pragma unroll
    for (int nt = 0; nt < 4; nt++)
#pragma unroll
      for (int r = 0; r < 4; r++) {
        int m = m0 + mt * 16 + quad * 4 + r;
        int c = c0 + nt * 16 + l15;
        out[(size_t)m * 1024 + c] = acc[mt][nt][r] + bias[c];
      }
}

extern "C" void kernel_launch(void* const* d_in, const int* in_sizes, int n_in,
                              void* d_out, int out_size, void* d_ws, size_t ws_size,
                              hipStream_t stream) {
  const float* x    = (const float*)d_in[0];
  const float* Wqkv = (const float*)d_in[1];
  const float* ab   = (const float*)d_in[2];
  // d_in[3] (bias_idxs) unused: idx == |n/32-m/32|*32 + |n%32-m%32| analytically
  const float* Wout = (const float*)d_in[4];
  const float* bout = (const float*)d_in[5];
  float* out = (float*)d_out;

  char* ws = (char*)d_ws;
  unsigned short* xb  = (unsigned short*)(ws);                    // 16 MB
  unsigned short* wqb = (unsigned short*)(ws + 16777216);         // 6 MB
  unsigned short* wob = (unsigned short*)(ws + 23068672);         // 2 MB
  unsigned short* qw  = (unsigned short*)(ws + 25165824);         // 16 MB
  unsigned short* kw  = (unsigned short*)(ws + 41943040);         // 16 MB
  unsigned short* vw  = (unsigned short*)(ws + 58720256);         // 16 MB (vT)
  unsigned short* ow  = (unsigned short*)(ws + 75497472);         // 16 MB

  cast3_kernel<<<1536, 256, 0, stream>>>(x, Wqkv, Wout, xb, wqb, wob);
  gemm_qkv<<<dim3(24, 64), 256, 0, stream>>>(xb, wqb, qw, kw, vw);
  attn_kernel<<<512, 256, 0, stream>>>(qw, kw, vw, ab, ow);
  gemm_out_k<<<dim3(8, 64), 256, 0, stream>>>(ow, wob, bout, out);
}